// Round 10
// baseline (464.697 us; speedup 1.0000x reference)
//
#include <hip/hip_runtime.h>
#include <math.h>

#define TB 4
#define TT 2048
#define TD 1024
#define TH 8
#define THD 128

typedef __attribute__((ext_vector_type(8))) short short8;
typedef __attribute__((ext_vector_type(4))) short short4v;
typedef __attribute__((ext_vector_type(4))) float float4v;
typedef __attribute__((ext_vector_type(16))) float float16v;

__device__ __forceinline__ short f2bf(float f) {
    union { float f; unsigned u; } v; v.f = f;
    unsigned r = v.u + 0x7FFFu + ((v.u >> 16) & 1u);
    return (short)(r >> 16);
}

__device__ __forceinline__ float bf2f(short s) {
    union { unsigned u; float f; } v;
    v.u = ((unsigned)(unsigned short)s) << 16;
    return v.f;
}

__device__ __forceinline__ short8 cvt8(float4v a, float4v b) {
    short8 r;
    r[0] = f2bf(a[0]); r[1] = f2bf(a[1]); r[2] = f2bf(a[2]); r[3] = f2bf(a[3]);
    r[4] = f2bf(b[0]); r[5] = f2bf(b[1]); r[6] = f2bf(b[2]); r[7] = f2bf(b[3]);
    return r;
}

// async 16B global -> LDS (wave-uniform LDS base + lane*16)
__device__ __forceinline__ void async16(const void* g, void* l) {
    __builtin_amdgcn_global_load_lds(
        (const __attribute__((address_space(1))) unsigned int*)g,
        (__attribute__((address_space(3))) unsigned int*)l, 16, 0, 0);
}

// ---------------------------------------------------------------------------
// One fused fp32->bf16 converter for x, y, Wq, Wk, Wv, Wo (pure BW).
// Flat 1D grid 10240 (+1 flag-zeroing block in fused mode).
// FIX vs R9: the flag block has 256 threads but 512 flags — each thread
// zeroes TWO entries (R9 left flags[256..511] garbage -> absmax 3.3).
// ---------------------------------------------------------------------------
__global__ void cvtall(const float* __restrict__ x, const float* __restrict__ y,
                       const float* __restrict__ wq, const float* __restrict__ wk,
                       const float* __restrict__ wv, const float* __restrict__ wo,
                       short* __restrict__ xyb, short* __restrict__ wb,
                       int* __restrict__ flags)
{
    const size_t SZ = (size_t)TB * TT * TD;
    const size_t WSZ = (size_t)TD * TD;
    const int bid = blockIdx.x;
    if (bid >= 10240) {                           // fused-combine flag init
        if (flags) {
            flags[threadIdx.x] = 0;
            flags[threadIdx.x + 256] = 0;
        }
        return;
    }
    const float* s; short* d; size_t base;
    if (bid < 8192) {
        int ty = bid >> 12;                       // 0 = x, 1 = y
        s = ty ? y : x;
        d = xyb + (size_t)ty * SZ;
        base = (size_t)(bid & 4095) * 2048;
    } else {
        int wi = bid - 8192;
        int w = wi >> 9;                          // 0..3
        s = (w == 0) ? wq : (w == 1) ? wk : (w == 2) ? wv : wo;
        d = wb + (size_t)w * WSZ;
        base = (size_t)(wi & 511) * 2048;
    }
    size_t i = base + (size_t)threadIdx.x * 8;
    float4v v0 = *(const float4v*)(s + i);
    float4v v1 = *(const float4v*)(s + i + 4);
    *(short8*)(d + i) = cvt8(v0, v1);
}

// ---------------------------------------------------------------------------
// 8-wave 256x128 NT-GEMM core, BK=64, 16 K-tiles. TWO phases per K-tile with
// counted lgkm (best-measured variant):
//  - issue ALL 16 ds_reads; lgkmcnt(4) -> 16 MFMA (ni 0..1)
//  - lgkmcnt(0) -> barrier; stage 6 gload_lds (tile it+2, SAME buffer)
//  - 16 MFMA (ni 2..3, no wait), vmcnt(6) counted, barrier
// 2 buffers give an effective 3-tile pipeline. LDS 96 KB -> 1 block/CU.
// ---------------------------------------------------------------------------
__device__ __forceinline__ void gemm_core256(const short* __restrict__ A,
                                             const short* __restrict__ W,
                                             int m0, int n0, short* SM,
                                             float4v acc[4][4])
{
    short* As = SM;             // 2 x (256x64)
    short* Bs = SM + 32768;     // 2 x (128x64)
    const int tid = threadIdx.x;
    const int lane = tid & 63, wid = tid >> 6;
    const int lr = lane & 15, qd = lane >> 4, sw = lane & 7;
    const int wr = wid >> 1, wc = wid & 1;
    const int rsub = lane >> 3;
    const int gj = ((lane & 7) ^ rsub) * 8;
    const int K = TD;

    const short* aSrc[4]; int aDst[4];
    const short* bSrc[2]; int bDst[2];
#pragma unroll
    for (int p = 0; p < 4; ++p) {
        int ch = wid * 4 + p;                     // 0..31, rows ch*8..+8
        aSrc[p] = A + (size_t)(m0 + ch * 8 + rsub) * K + gj;
        aDst[p] = ch * 512;
    }
#pragma unroll
    for (int p = 0; p < 2; ++p) {
        int ch = wid * 2 + p;                     // 0..15
        bSrc[p] = W + (size_t)(n0 + ch * 8 + rsub) * K + gj;
        bDst[p] = ch * 512;
    }

#pragma unroll
    for (int mt = 0; mt < 4; ++mt)
#pragma unroll
        for (int nt = 0; nt < 4; ++nt)
            acc[mt][nt] = float4v{0.f, 0.f, 0.f, 0.f};

    // prologue: stage K-tiles 0 (buf0) and 1 (buf1); wait tile 0 (6 calls/wave)
#pragma unroll
    for (int t = 0; t < 2; ++t) {
#pragma unroll
        for (int p = 0; p < 4; ++p)
            async16(aSrc[p] + t * 64, As + t * 16384 + aDst[p]);
#pragma unroll
        for (int p = 0; p < 2; ++p)
            async16(bSrc[p] + t * 64, Bs + t * 8192 + bDst[p]);
    }
    asm volatile("s_waitcnt vmcnt(6)" ::: "memory");
    __builtin_amdgcn_sched_barrier(0);
    __builtin_amdgcn_s_barrier();

#pragma unroll 2
    for (int it = 0; it < 16; ++it) {
        const short* Ac = As + (it & 1) * 16384;
        const short* Bc = Bs + (it & 1) * 8192;
        short* Asn = As + (it & 1) * 16384;   // stage dest = same buffer
        short* Bsn = Bs + (it & 1) * 8192;
        const int kb2 = (it + 2) * 64;
        const bool stg = (it < 14);

        short8 af[4][2], bf[4][2];

        // ---- reads, group 1: all A (8) + B nh0 (4) — consumed by MFMA1
#pragma unroll
        for (int mi = 0; mi < 4; ++mi)
#pragma unroll
            for (int ks = 0; ks < 2; ++ks)
                af[mi][ks] = *(const short8*)&Ac[(wr * 64 + mi * 16 + lr) * 64 +
                                                 (((ks * 4 + qd) ^ sw) * 8)];
#pragma unroll
        for (int ni = 0; ni < 2; ++ni)
#pragma unroll
            for (int ks = 0; ks < 2; ++ks)
                bf[ni][ks] = *(const short8*)&Bc[(wc * 64 + ni * 16 + lr) * 64 +
                                                 (((ks * 4 + qd) ^ sw) * 8)];
        __builtin_amdgcn_sched_barrier(0);
        // ---- reads, group 2: B nh1 (4) — consumed by MFMA2 (stay outstanding)
#pragma unroll
        for (int ni = 2; ni < 4; ++ni)
#pragma unroll
            for (int ks = 0; ks < 2; ++ks)
                bf[ni][ks] = *(const short8*)&Bc[(wc * 64 + ni * 16 + lr) * 64 +
                                                 (((ks * 4 + qd) ^ sw) * 8)];
        asm volatile("s_waitcnt lgkmcnt(4)" ::: "memory");
        __builtin_amdgcn_sched_barrier(0);
        __builtin_amdgcn_s_setprio(1);
#pragma unroll
        for (int mi = 0; mi < 4; ++mi)
#pragma unroll
            for (int ni = 0; ni < 2; ++ni)
#pragma unroll
                for (int ks = 0; ks < 2; ++ks)
                    acc[mi][ni] = __builtin_amdgcn_mfma_f32_16x16x32_bf16(
                        af[mi][ks], bf[ni][ks], acc[mi][ni], 0, 0, 0);
        __builtin_amdgcn_s_setprio(0);
        __builtin_amdgcn_sched_barrier(0);
        asm volatile("s_waitcnt lgkmcnt(0)" ::: "memory");
        __builtin_amdgcn_sched_barrier(0);
        __builtin_amdgcn_s_barrier();          // all reads of this buffer done
        __builtin_amdgcn_sched_barrier(0);

        // ---- stage tile it+2 into the just-fully-read buffer
        if (stg) {
#pragma unroll
            for (int p = 0; p < 4; ++p)
                async16(aSrc[p] + kb2, Asn + aDst[p]);
#pragma unroll
            for (int p = 0; p < 2; ++p)
                async16(bSrc[p] + kb2, Bsn + bDst[p]);
        }
        __builtin_amdgcn_s_setprio(1);
#pragma unroll
        for (int mi = 0; mi < 4; ++mi)
#pragma unroll
            for (int ni = 2; ni < 4; ++ni)
#pragma unroll
                for (int ks = 0; ks < 2; ++ks)
                    acc[mi][ni] = __builtin_amdgcn_mfma_f32_16x16x32_bf16(
                        af[mi][ks], bf[ni][ks], acc[mi][ni], 0, 0, 0);
        __builtin_amdgcn_s_setprio(0);
        if (stg) { asm volatile("s_waitcnt vmcnt(6)" ::: "memory"); }
        else     { asm volatile("s_waitcnt vmcnt(0)" ::: "memory"); }
        __builtin_amdgcn_sched_barrier(0);
        __builtin_amdgcn_s_barrier();
    }
}

// ---------------------------------------------------------------------------
// Fused QKV GEMM, 8-wave 256x128 tiles. 1D grid 768 (= 3 exact CU-waves),
// bijective XCD swizzle, by-major chunks (A-panels L2-resident per XCD).
// ---------------------------------------------------------------------------
__global__ __launch_bounds__(512, 2)
void gemm_qkv8(const short* __restrict__ xyb, const short* __restrict__ wb,
               const float* __restrict__ bq, const float* __restrict__ bk,
               const float* __restrict__ bv,
               short* __restrict__ qhp, short* __restrict__ khp,
               short* __restrict__ vtp)
{
    __shared__ __attribute__((aligned(16))) short SM[49152];  // 96 KB
    const size_t SZ = (size_t)TB * TT * TD;
    const int bid = blockIdx.x;
    const int lin = (bid & 7) * 96 + (bid >> 3);   // XCD chunks of 96
    const int by = lin / 24, bx = lin - by * 24;
    const int mode = bx >> 3;                      // 0=Q, 1=K, 2=V
    const int n0 = (bx & 7) * 128;
    const int h_ = n0 >> 7;
    const int m0 = by * 256;
    const short* A = (mode == 0) ? xyb : (xyb + SZ);
    const short* W = wb + (size_t)mode * TD * TD;
    const float* bias = (mode == 0) ? bq : (mode == 1) ? bk : bv;
    // Q gets 1/sqrt(HD) * log2(e) so attention can use exp2 directly
    const float scale = (mode == 0)
        ? (0.08838834764831845f * 1.4426950408889634f) : 1.0f;

    float4v acc[4][4];
    gemm_core256(A, W, m0, n0, SM, acc);

    const int tid = threadIdx.x;
    const int lane = tid & 63, wid = tid >> 6;
    const int lr = lane & 15, qd = lane >> 4;
    const int wr = wid >> 1, wc = wid & 1;

    // ---- epilogue via LDS: bias+scale+cvt, then coalesced 16B stores ----
#pragma unroll
    for (int nt = 0; nt < 4; ++nt) {
        int col = wc * 64 + nt * 16 + lr;          // hd within head
        float bi = bias[n0 + col];
#pragma unroll
        for (int mt = 0; mt < 4; ++mt)
#pragma unroll
            for (int i = 0; i < 4; ++i) {
                int row = wr * 64 + mt * 16 + qd * 4 + i;   // t within tile
                short v = f2bf((acc[mt][nt][i] + bi) * scale);
                if (mode < 2) SM[row * 128 + col] = v;      // [t][hd]
                else          SM[col * 264 + row] = v;      // [hd][t], pad
            }
    }
    __syncthreads();

    if (mode < 2) {
        short* outp = (mode == 0) ? qhp : khp;
#pragma unroll
        for (int r8 = 0; r8 < 8; ++r8) {
            int row = r8 * 32 + (tid >> 4), c = tid & 15;
            short8 v = *(const short8*)&SM[row * 128 + c * 8];
            int tg = m0 + row;
            int b_ = tg >> 11, t_ = tg & (TT - 1);
            *(short8*)&outp[(((size_t)(b_ * TH + h_)) * TT + t_) * THD + c * 8] = v;
        }
    } else {
        int b_ = m0 >> 11, t0 = m0 & (TT - 1);
#pragma unroll
        for (int r8 = 0; r8 < 8; ++r8) {
            int hd = r8 * 16 + (tid >> 5), c = tid & 31;
            short8 v = *(const short8*)&SM[hd * 264 + c * 8];
            *(short8*)&vtp[(((size_t)(b_ * TH + h_)) * THD + hd) * TT + t0 + c * 8] = v;
        }
    }
}

// ---------------------------------------------------------------------------
// Output-projection GEMM, 8-wave 256x128 tiles. 256 blocks = 1 exact CU-wave.
// ---------------------------------------------------------------------------
__global__ __launch_bounds__(512, 2)
void gemm_out8(const short* __restrict__ A, const short* __restrict__ W,
               const float* __restrict__ bias, float* __restrict__ outp)
{
    __shared__ __attribute__((aligned(16))) short SM[49152];
    const int bid = blockIdx.x;                    // 256
    const int lin = (bid & 7) * 32 + (bid >> 3);   // XCD chunks of 32
    const int by = lin >> 3, bx = lin & 7;
    const int m0 = by * 256, n0 = bx * 128;

    float4v acc[4][4];
    gemm_core256(A, W, m0, n0, SM, acc);

    const int tid = threadIdx.x;
    const int lane = tid & 63, wid = tid >> 6;
    const int lr = lane & 15, qd = lane >> 4;
    const int wr = wid >> 1, wc = wid & 1;
#pragma unroll
    for (int nt = 0; nt < 4; ++nt) {
        int col = n0 + wc * 64 + nt * 16 + lr;
        float bi = bias[col];
#pragma unroll
        for (int mt = 0; mt < 4; ++mt)
#pragma unroll
            for (int i = 0; i < 4; ++i) {
                int row = m0 + wr * 64 + mt * 16 + qd * 4 + i;
                outp[(size_t)row * TD + col] = acc[mt][nt][i] + bi;
            }
    }
}

// ---------------------------------------------------------------------------
// Flash attention, causal, KV-split (17 uniform iters/block, 512 blocks).
// (1) P->bf16 via v_cvt_pk_bf16_f32 (1 op per 2 values, same RNE as f2bf);
// (2) FUSED COMBINE: tile (bh,qt)'s two halves come from blocks j=qt and
// j=15-qt. Each block writes its partial (po,pl), release-fences, and
// atomicAdd(&flags[tile],1). The block seeing old==1 acquires, reads the
// other half (L2-hot), normalizes with its IN-REGISTER o/li, writes ctx,
// and resets the flag. flags==nullptr -> fusion disabled (combine kernel).
// ---------------------------------------------------------------------------
__global__ __launch_bounds__(256, 2)
void attn_fwd(const short* __restrict__ qh, const short* __restrict__ kh,
              const short* __restrict__ vt, short* __restrict__ po,
              float* __restrict__ pl, int* __restrict__ flags,
              short* __restrict__ ctx)
{
    __shared__ __attribute__((aligned(16))) short Ks[2][64 * 128];  // [key][hd]
    __shared__ __attribute__((aligned(16))) short Vs[2][128 * 64];  // [hd][key]
    __shared__ int s_old;

    const int tid = threadIdx.x;
    const int lane = tid & 63, wid = tid >> 6;   // 4 waves
    const int l31 = lane & 31, h = lane >> 5;
    const int sw7 = l31 & 7;

    const int bi = blockIdx.x;
    const int bh = bi & 31;          // bh%8 == bi%8 -> all 16 blocks of a bh
    const int j  = bi >> 5;          // land on one XCD (K/V L2-resident)
    const size_t bho = (size_t)bh * TT * THD;

    for (int u = 0; u < 2; ++u) {
        const int qt  = u ? (15 - j) : j;
        const int kv0 = u ? (qt + 1) : 0;
        const int kv1 = u ? (2 * qt + 2) : (j + 1);

        // Q B-frags for this tile: B[k=hd][n=q=l31]
        short8 qf[8];
        {
            const short* qp = qh + bho + (size_t)(qt * 128 + wid * 32 + l31) * THD;
#pragma unroll
            for (int ks = 0; ks < 8; ++ks)
                qf[ks] = *(const short8*)(qp + ks * 16 + h * 8);
        }
        float16v o[4];
#pragma unroll
        for (int db = 0; db < 4; ++db)
#pragma unroll
            for (int r = 0; r < 16; ++r) o[db][r] = 0.f;
        float li = 0.f;

        // prologue: stage first tile into buf 0
        {
            const short* kbase = kh + bho + (size_t)kv0 * 64 * THD;
            const short* vbase = vt + (size_t)bh * THD * TT + (size_t)kv0 * 64;
#pragma unroll
            for (int p = 0; p < 4; ++p) {
                int ch = wid * 4 + p;
                int kr = ch * 4 + (lane >> 4);
                int kg = (lane & 15) ^ (kr & 7);
                async16(kbase + (size_t)kr * THD + kg * 8, &Ks[0][ch * 512]);
                int vr = ch * 8 + (lane >> 3);
                int vg = (lane & 7) ^ (vr & 7);
                async16(vbase + (size_t)vr * TT + vg * 8, &Vs[0][ch * 512]);
            }
        }
        __syncthreads();   // drains vmcnt (compiler) + joins waves

        int cur = 0;
        for (int kv = kv0; kv < kv1; ++kv) {
            // issue next tile's loads into the other buffer (hidden by compute)
            if (kv + 1 < kv1) {
                const short* kbase = kh + bho + (size_t)(kv + 1) * 64 * THD;
                const short* vbase = vt + (size_t)bh * THD * TT +
                                     (size_t)(kv + 1) * 64;
#pragma unroll
                for (int p = 0; p < 4; ++p) {
                    int ch = wid * 4 + p;
                    int kr = ch * 4 + (lane >> 4);
                    int kg = (lane & 15) ^ (kr & 7);
                    async16(kbase + (size_t)kr * THD + kg * 8,
                            &Ks[cur ^ 1][ch * 512]);
                    int vr = ch * 8 + (lane >> 3);
                    int vg = (lane & 7) ^ (vr & 7);
                    async16(vbase + (size_t)vr * TT + vg * 8,
                            &Vs[cur ^ 1][ch * 512]);
                }
            }

            const short* Kc = Ks[cur];
            const short* Vc = Vs[cur];

            // S^T = K * Q^T : A = K (m=key), B = Q (n=q). 2 key-blocks of 32.
            float16v s[2];
#pragma unroll
            for (int kb = 0; kb < 2; ++kb)
#pragma unroll
                for (int r = 0; r < 16; ++r) s[kb][r] = 0.f;
#pragma unroll
            for (int ks = 0; ks < 8; ++ks) {
                int cidx = ((ks * 2 + h) ^ sw7) * 8;
                short8 kf0 = *(const short8*)&Kc[l31 * 128 + cidx];
                short8 kf1 = *(const short8*)&Kc[(32 + l31) * 128 + cidx];
                s[0] = __builtin_amdgcn_mfma_f32_32x32x16_bf16(kf0, qf[ks], s[0], 0, 0, 0);
                s[1] = __builtin_amdgcn_mfma_f32_32x32x16_bf16(kf1, qf[ks], s[1], 0, 0, 0);
            }

            if (kv >= 2 * qt) {   // diagonal region: elementwise causal mask
                int q = qt * 128 + wid * 32 + l31;
#pragma unroll
                for (int r = 0; r < 16; ++r) {
                    int key = kv * 64 + (r & 3) + 8 * (r >> 2) + 4 * h;
                    if (key > q) s[0][r] = -1e30f;
                    if (key + 32 > q) s[1][r] = -1e30f;
                }
            }

            // P = exp2(S^T) -> bf16 A-frags via v_cvt_pk_bf16_f32 (RNE, same
            // rounding as f2bf; 1 op per 2 values vs 4 ops per value)
#pragma unroll
            for (int st = 0; st < 8; ++st) {
                float e0 = exp2f(s[st >> 2][(st & 3) * 4 + 0]);
                float e1 = exp2f(s[st >> 2][(st & 3) * 4 + 1]);
                float e2 = exp2f(s[st >> 2][(st & 3) * 4 + 2]);
                float e3 = exp2f(s[st >> 2][(st & 3) * 4 + 3]);
                li += (e0 + e1) + (e2 + e3);
                unsigned p0, p1;
                asm("v_cvt_pk_bf16_f32 %0, %1, %2" : "=v"(p0) : "v"(e0), "v"(e1));
                asm("v_cvt_pk_bf16_f32 %0, %1, %2" : "=v"(p1) : "v"(e2), "v"(e3));
                union { unsigned u[2]; short4v s4; } pk;
                pk.u[0] = p0; pk.u[1] = p1;
                const short4v ap = pk.s4;
#pragma unroll
                for (int db = 0; db < 4; ++db) {
                    short4v vf = *(const short4v*)&Vc[(db * 32 + l31) * 64 +
                                                      ((st ^ sw7) * 8) + h * 4];
                    o[db] = __builtin_amdgcn_mfma_f32_32x32x8bf16_1k(ap, vf, o[db], 0, 0, 0);
                }
            }
            __syncthreads();   // staged loads drained + all reads of cur done
            cur ^= 1;
        }

        // ---- write partial (O bf16, l fp32) for slot (bh, qt, u) ----
        li += __shfl_xor(li, 32);
        const int slot = (bh * 16 + qt) * 2 + u;
        if (h == 0) pl[slot * 128 + wid * 32 + l31] = li;
        short* pop = po + (size_t)slot * 16384 + (size_t)(wid * 32) * 128 + l31;
#pragma unroll
        for (int r = 0; r < 16; ++r) {
            int ql = (r & 3) + 8 * (r >> 2) + 4 * h;
#pragma unroll
            for (int db = 0; db < 4; ++db)
                pop[(size_t)ql * 128 + db * 32] = f2bf(o[db][r]);
        }

        if (flags) {   // fused combine: last arriver normalizes the tile
            const int tile = bh * 16 + qt;
            __threadfence();                       // release own po/pl stores
            __syncthreads();
            if (tid == 0) s_old = atomicAdd(&flags[tile], 1);
            __syncthreads();
            if (s_old == 1) {
                __threadfence();                   // acquire other half
                const int oslot = tile * 2 + (1 - u);
                const short* opo = po + (size_t)oslot * 16384;
                const float* opl = pl + (size_t)oslot * 128;
                const int b_ = bh >> 3, h_ = bh & 7;
                short* cb = ctx + ((size_t)(b_ * TT + qt * 128 + wid * 32)) * TD
                            + (size_t)h_ * THD + l31;
#pragma unroll
                for (int r = 0; r < 16; ++r) {
                    int ql = (r & 3) + 8 * (r >> 2) + 4 * h;
                    float lq = __shfl(li, ql, 32);
                    float inv = 1.f / (lq + opl[wid * 32 + ql]);
                    const short* ob = opo + (size_t)(wid * 32 + ql) * 128 + l31;
                    short* cp = cb + (size_t)ql * TD;
#pragma unroll
                    for (int db = 0; db < 4; ++db)
                        cp[db * 32] = f2bf((o[db][r] + bf2f(ob[db * 32])) * inv);
                }
                __syncthreads();
                if (tid == 0) flags[tile] = 0;     // self-reset for next launch
            }
        }
    }
}

// ---------------------------------------------------------------------------
// Combine the two KV-halves: ctx = (oA + oB) / (lA + lB), bf16 out.
// (fallback path only, when workspace is too small for a separate ctx)
// ---------------------------------------------------------------------------
__global__ __launch_bounds__(256)
void combine(const short* __restrict__ po, const float* __restrict__ pl,
             short* __restrict__ ctx)
{
    const unsigned i = blockIdx.x * 256 + threadIdx.x;   // [0, 1<<20)
    const int hdv = i & 15;
    const int q   = (i >> 4) & 127;
    const int qt  = (i >> 11) & 15;
    const int bh  = i >> 15;                              // [0,32)
    const int tile = bh * 16 + qt;
    const size_t base = (size_t)tile * 2 * 16384 + (size_t)q * 128 + hdv * 8;
    short8 a = *(const short8*)&po[base];
    short8 b = *(const short8*)&po[base + 16384];
    const float inv = 1.f / (pl[tile * 2 * 128 + q] + pl[(tile * 2 + 1) * 128 + q]);
    short8 r;
#pragma unroll
    for (int k = 0; k < 8; ++k)
        r[k] = f2bf((bf2f(a[k]) + bf2f(b[k])) * inv);
    const int b_ = bh >> 3, h_ = bh & 7, t = qt * 128 + q;
    *(short8*)&ctx[((size_t)(b_ * TT + t)) * TD + h_ * THD + hdv * 8] = r;
}

extern "C" void kernel_launch(void* const* d_in, const int* in_sizes, int n_in,
                              void* d_out, int out_size, void* d_ws, size_t ws_size,
                              hipStream_t stream) {
    (void)in_sizes; (void)n_in; (void)out_size;
    const float* x  = (const float*)d_in[0];
    const float* y  = (const float*)d_in[1];
    const float* Wq = (const float*)d_in[2];
    const float* bq = (const float*)d_in[3];
    const float* Wk = (const float*)d_in[4];
    const float* bk = (const float*)d_in[5];
    const float* Wv = (const float*)d_in[6];
    const float* bv = (const float*)d_in[7];
    const float* Wo = (const float*)d_in[8];
    const float* bo = (const float*)d_in[9];
    float* out = (float*)d_out;

    const size_t SZ = (size_t)TB * TT * TD;     // 8,388,608
    const size_t WSZ = (size_t)TD * TD;         // 1,048,576
    short* xyb = (short*)d_ws;                  // x,y bf16 (33.5 MB)
    short* wb  = xyb + 2 * SZ;                  // weights bf16 (8 MB)
    short* qh  = wb + 4 * WSZ;
    short* kh  = qh + SZ;
    short* vt  = kh + SZ;
    float* pl  = (float*)(vt + SZ);             // partial l, 512 KB
    int* flagp = (int*)(pl + 1024 * 128);       // 512 tile flags (2 KB)
    short* ctxf = (short*)(flagp + 512);        // fused-mode ctx (16.8 MB)
    short* po  = xyb;                           // partial O: aliases dead x/y

    // bytes needed for the fused layout (separate ctx region)
    const size_t need = (size_t)(6 * SZ + 4 * WSZ) * 2
                        + 1024 * 128 * 4 + 512 * 4 + SZ * 2;
    const bool fused = (ws_size >= need);
    short* ctx = fused ? ctxf : qh;             // fallback: ctx aliases qh

    hipLaunchKernelGGL(cvtall, dim3(fused ? 10241 : 10240), dim3(256), 0, stream,
                       x, y, Wq, Wk, Wv, Wo, xyb, wb, fused ? flagp : nullptr);
    hipLaunchKernelGGL(gemm_qkv8, dim3(768), dim3(512), 0, stream,
                       xyb, wb, bq, bk, bv, qh, kh, vt);
    hipLaunchKernelGGL(attn_fwd, dim3(512), dim3(256), 0, stream,
                       qh, kh, vt, po, pl, fused ? flagp : nullptr, ctx);
    if (!fused)
        hipLaunchKernelGGL(combine, dim3(4096), dim3(256), 0, stream, po, pl, ctx);
    hipLaunchKernelGGL(gemm_out8, dim3(256), dim3(512), 0, stream,
                       ctx, wb + 3 * WSZ, bo, out);
}

// Round 12
// 275.970 us; speedup vs baseline: 1.6839x; 1.6839x over previous
//
#include <hip/hip_runtime.h>
#include <math.h>

#define TB 4
#define TT 2048
#define TD 1024
#define TH 8
#define THD 128

typedef __attribute__((ext_vector_type(8))) short short8;
typedef __attribute__((ext_vector_type(4))) short short4v;
typedef __attribute__((ext_vector_type(4))) float float4v;
typedef __attribute__((ext_vector_type(16))) float float16v;

__device__ __forceinline__ short f2bf(float f) {
    union { float f; unsigned u; } v; v.f = f;
    unsigned r = v.u + 0x7FFFu + ((v.u >> 16) & 1u);
    return (short)(r >> 16);
}

__device__ __forceinline__ float bf2f(short s) {
    union { unsigned u; float f; } v;
    v.u = ((unsigned)(unsigned short)s) << 16;
    return v.f;
}

__device__ __forceinline__ short8 cvt8(float4v a, float4v b) {
    short8 r;
    r[0] = f2bf(a[0]); r[1] = f2bf(a[1]); r[2] = f2bf(a[2]); r[3] = f2bf(a[3]);
    r[4] = f2bf(b[0]); r[5] = f2bf(b[1]); r[6] = f2bf(b[2]); r[7] = f2bf(b[3]);
    return r;
}

// async 16B global -> LDS (wave-uniform LDS base + lane*16)
__device__ __forceinline__ void async16(const void* g, void* l) {
    __builtin_amdgcn_global_load_lds(
        (const __attribute__((address_space(1))) unsigned int*)g,
        (__attribute__((address_space(3))) unsigned int*)l, 16, 0, 0);
}

// ---------------------------------------------------------------------------
// One fused fp32->bf16 converter for x, y, Wq, Wk, Wv, Wo (pure BW).
// ---------------------------------------------------------------------------
__global__ void cvtall(const float* __restrict__ x, const float* __restrict__ y,
                       const float* __restrict__ wq, const float* __restrict__ wk,
                       const float* __restrict__ wv, const float* __restrict__ wo,
                       short* __restrict__ xyb, short* __restrict__ wb)
{
    const size_t SZ = (size_t)TB * TT * TD;
    const size_t WSZ = (size_t)TD * TD;
    int ty = blockIdx.y;
    const float* s; short* d; size_t n;
    if (ty == 0)      { s = x;  d = xyb;      n = SZ; }
    else if (ty == 1) { s = y;  d = xyb + SZ; n = SZ; }
    else {
        s = (ty == 2) ? wq : (ty == 3) ? wk : (ty == 4) ? wv : wo;
        d = wb + (size_t)(ty - 2) * WSZ; n = WSZ;
    }
    size_t i = ((size_t)blockIdx.x * blockDim.x + threadIdx.x) * 8;
    if (i >= n) return;
    float4v v0 = *(const float4v*)(s + i);
    float4v v1 = *(const float4v*)(s + i + 4);
    *(short8*)(d + i) = cvt8(v0, v1);
}

// ---------------------------------------------------------------------------
// 8-wave 256x128 NT-GEMM core, BK=64, 16 K-tiles. TWO phases per K-tile with
// counted lgkm (best-measured variant, benched 278.1us):
//  - issue ALL 16 ds_reads (order pinned: af x8, bf[0..1] x4 | bf[2..3] x4)
//  - lgkmcnt(4)  -> first 12 done -> 16 MFMA (ni 0..1)
//  - lgkmcnt(0)  -> barrier       (all waves' reads of this buffer complete)
//  - stage 6 gload_lds (tile it+2, SAME buffer - safe after barrier)
//  - 16 MFMA (ni 2..3, no wait), vmcnt(6) counted, barrier
// 2 buffers give an effective 3-tile pipeline. LDS 96 KB -> 1 block/CU.
// ---------------------------------------------------------------------------
__device__ __forceinline__ void gemm_core256(const short* __restrict__ A,
                                             const short* __restrict__ W,
                                             int m0, int n0, short* SM,
                                             float4v acc[4][4])
{
    short* As = SM;             // 2 x (256x64)
    short* Bs = SM + 32768;     // 2 x (128x64)
    const int tid = threadIdx.x;
    const int lane = tid & 63, wid = tid >> 6;
    const int lr = lane & 15, qd = lane >> 4, sw = lane & 7;
    const int wr = wid >> 1, wc = wid & 1;
    const int rsub = lane >> 3;
    const int gj = ((lane & 7) ^ rsub) * 8;
    const int K = TD;

    const short* aSrc[4]; int aDst[4];
    const short* bSrc[2]; int bDst[2];
#pragma unroll
    for (int p = 0; p < 4; ++p) {
        int ch = wid * 4 + p;                     // 0..31, rows ch*8..+8
        aSrc[p] = A + (size_t)(m0 + ch * 8 + rsub) * K + gj;
        aDst[p] = ch * 512;
    }
#pragma unroll
    for (int p = 0; p < 2; ++p) {
        int ch = wid * 2 + p;                     // 0..15
        bSrc[p] = W + (size_t)(n0 + ch * 8 + rsub) * K + gj;
        bDst[p] = ch * 512;
    }

#pragma unroll
    for (int mt = 0; mt < 4; ++mt)
#pragma unroll
        for (int nt = 0; nt < 4; ++nt)
            acc[mt][nt] = float4v{0.f, 0.f, 0.f, 0.f};

    // prologue: stage K-tiles 0 (buf0) and 1 (buf1); wait tile 0 (6 calls/wave)
#pragma unroll
    for (int t = 0; t < 2; ++t) {
#pragma unroll
        for (int p = 0; p < 4; ++p)
            async16(aSrc[p] + t * 64, As + t * 16384 + aDst[p]);
#pragma unroll
        for (int p = 0; p < 2; ++p)
            async16(bSrc[p] + t * 64, Bs + t * 8192 + bDst[p]);
    }
    asm volatile("s_waitcnt vmcnt(6)" ::: "memory");
    __builtin_amdgcn_sched_barrier(0);
    __builtin_amdgcn_s_barrier();

#pragma unroll 2
    for (int it = 0; it < 16; ++it) {
        const short* Ac = As + (it & 1) * 16384;
        const short* Bc = Bs + (it & 1) * 8192;
        short* Asn = As + (it & 1) * 16384;   // stage dest = same buffer
        short* Bsn = Bs + (it & 1) * 8192;
        const int kb2 = (it + 2) * 64;
        const bool stg = (it < 14);

        short8 af[4][2], bf[4][2];

        // ---- reads, group 1: all A (8) + B nh0 (4) — consumed by MFMA1
#pragma unroll
        for (int mi = 0; mi < 4; ++mi)
#pragma unroll
            for (int ks = 0; ks < 2; ++ks)
                af[mi][ks] = *(const short8*)&Ac[(wr * 64 + mi * 16 + lr) * 64 +
                                                 (((ks * 4 + qd) ^ sw) * 8)];
#pragma unroll
        for (int ni = 0; ni < 2; ++ni)
#pragma unroll
            for (int ks = 0; ks < 2; ++ks)
                bf[ni][ks] = *(const short8*)&Bc[(wc * 64 + ni * 16 + lr) * 64 +
                                                 (((ks * 4 + qd) ^ sw) * 8)];
        __builtin_amdgcn_sched_barrier(0);
        // ---- reads, group 2: B nh1 (4) — consumed by MFMA2 (stay outstanding)
#pragma unroll
        for (int ni = 2; ni < 4; ++ni)
#pragma unroll
            for (int ks = 0; ks < 2; ++ks)
                bf[ni][ks] = *(const short8*)&Bc[(wc * 64 + ni * 16 + lr) * 64 +
                                                 (((ks * 4 + qd) ^ sw) * 8)];
        asm volatile("s_waitcnt lgkmcnt(4)" ::: "memory");
        __builtin_amdgcn_sched_barrier(0);
        __builtin_amdgcn_s_setprio(1);
#pragma unroll
        for (int mi = 0; mi < 4; ++mi)
#pragma unroll
            for (int ni = 0; ni < 2; ++ni)
#pragma unroll
                for (int ks = 0; ks < 2; ++ks)
                    acc[mi][ni] = __builtin_amdgcn_mfma_f32_16x16x32_bf16(
                        af[mi][ks], bf[ni][ks], acc[mi][ni], 0, 0, 0);
        __builtin_amdgcn_s_setprio(0);
        __builtin_amdgcn_sched_barrier(0);
        asm volatile("s_waitcnt lgkmcnt(0)" ::: "memory");
        __builtin_amdgcn_sched_barrier(0);
        __builtin_amdgcn_s_barrier();          // all reads of this buffer done
        __builtin_amdgcn_sched_barrier(0);

        // ---- stage tile it+2 into the just-fully-read buffer
        if (stg) {
#pragma unroll
            for (int p = 0; p < 4; ++p)
                async16(aSrc[p] + kb2, Asn + aDst[p]);
#pragma unroll
            for (int p = 0; p < 2; ++p)
                async16(bSrc[p] + kb2, Bsn + bDst[p]);
        }
        __builtin_amdgcn_s_setprio(1);
#pragma unroll
        for (int mi = 0; mi < 4; ++mi)
#pragma unroll
            for (int ni = 2; ni < 4; ++ni)
#pragma unroll
                for (int ks = 0; ks < 2; ++ks)
                    acc[mi][ni] = __builtin_amdgcn_mfma_f32_16x16x32_bf16(
                        af[mi][ks], bf[ni][ks], acc[mi][ni], 0, 0, 0);
        __builtin_amdgcn_s_setprio(0);
        if (stg) { asm volatile("s_waitcnt vmcnt(6)" ::: "memory"); }
        else     { asm volatile("s_waitcnt vmcnt(0)" ::: "memory"); }
        __builtin_amdgcn_sched_barrier(0);
        __builtin_amdgcn_s_barrier();
    }
}

// ---------------------------------------------------------------------------
// Fused QKV GEMM, 8-wave 256x128 tiles. 1D grid 768 (= 3 exact CU-waves),
// bijective XCD swizzle, by-major chunks (A-panels L2-resident per XCD).
// bx 0-7 = Q, 8-15 = K, 16-23 = V; each 128-col tile = one head.
// ---------------------------------------------------------------------------
__global__ __launch_bounds__(512, 2)
void gemm_qkv8(const short* __restrict__ xyb, const short* __restrict__ wb,
               const float* __restrict__ bq, const float* __restrict__ bk,
               const float* __restrict__ bv,
               short* __restrict__ qhp, short* __restrict__ khp,
               short* __restrict__ vtp)
{
    __shared__ __attribute__((aligned(16))) short SM[49152];  // 96 KB
    const size_t SZ = (size_t)TB * TT * TD;
    const int bid = blockIdx.x;
    const int lin = (bid & 7) * 96 + (bid >> 3);   // XCD chunks of 96
    const int by = lin / 24, bx = lin - by * 24;
    const int mode = bx >> 3;                      // 0=Q, 1=K, 2=V
    const int n0 = (bx & 7) * 128;
    const int h_ = n0 >> 7;
    const int m0 = by * 256;
    const short* A = (mode == 0) ? xyb : (xyb + SZ);
    const short* W = wb + (size_t)mode * TD * TD;
    const float* bias = (mode == 0) ? bq : (mode == 1) ? bk : bv;
    // Q gets 1/sqrt(HD) * log2(e) so attention can use exp2 directly
    const float scale = (mode == 0)
        ? (0.08838834764831845f * 1.4426950408889634f) : 1.0f;

    float4v acc[4][4];
    gemm_core256(A, W, m0, n0, SM, acc);

    const int tid = threadIdx.x;
    const int lane = tid & 63, wid = tid >> 6;
    const int lr = lane & 15, qd = lane >> 4;
    const int wr = wid >> 1, wc = wid & 1;

    // ---- epilogue via LDS: bias+scale+cvt, then coalesced 16B stores ----
#pragma unroll
    for (int nt = 0; nt < 4; ++nt) {
        int col = wc * 64 + nt * 16 + lr;          // hd within head
        float bi = bias[n0 + col];
#pragma unroll
        for (int mt = 0; mt < 4; ++mt)
#pragma unroll
            for (int i = 0; i < 4; ++i) {
                int row = wr * 64 + mt * 16 + qd * 4 + i;   // t within tile
                short v = f2bf((acc[mt][nt][i] + bi) * scale);
                if (mode < 2) SM[row * 128 + col] = v;      // [t][hd]
                else          SM[col * 264 + row] = v;      // [hd][t], pad
            }
    }
    __syncthreads();

    if (mode < 2) {
        short* outp = (mode == 0) ? qhp : khp;
#pragma unroll
        for (int r8 = 0; r8 < 8; ++r8) {
            int row = r8 * 32 + (tid >> 4), c = tid & 15;
            short8 v = *(const short8*)&SM[row * 128 + c * 8];
            int tg = m0 + row;
            int b_ = tg >> 11, t_ = tg & (TT - 1);
            *(short8*)&outp[(((size_t)(b_ * TH + h_)) * TT + t_) * THD + c * 8] = v;
        }
    } else {
        int b_ = m0 >> 11, t0 = m0 & (TT - 1);
#pragma unroll
        for (int r8 = 0; r8 < 8; ++r8) {
            int hd = r8 * 16 + (tid >> 5), c = tid & 31;
            short8 v = *(const short8*)&SM[hd * 264 + c * 8];
            *(short8*)&vtp[(((size_t)(b_ * TH + h_)) * THD + hd) * TT + t0 + c * 8] = v;
        }
    }
}

// ---------------------------------------------------------------------------
// Output-projection GEMM, 8-wave 256x128 tiles. 256 blocks = 1 exact CU-wave.
// ---------------------------------------------------------------------------
__global__ __launch_bounds__(512, 2)
void gemm_out8(const short* __restrict__ A, const short* __restrict__ W,
               const float* __restrict__ bias, float* __restrict__ outp)
{
    __shared__ __attribute__((aligned(16))) short SM[49152];
    const int bid = blockIdx.x;                    // 256
    const int lin = (bid & 7) * 32 + (bid >> 3);   // XCD chunks of 32
    const int by = lin >> 3, bx = lin & 7;
    const int m0 = by * 256, n0 = bx * 128;

    float4v acc[4][4];
    gemm_core256(A, W, m0, n0, SM, acc);

    const int tid = threadIdx.x;
    const int lane = tid & 63, wid = tid >> 6;
    const int lr = lane & 15, qd = lane >> 4;
    const int wr = wid >> 1, wc = wid & 1;
#pragma unroll
    for (int nt = 0; nt < 4; ++nt) {
        int col = n0 + wc * 64 + nt * 16 + lr;
        float bi = bias[col];
#pragma unroll
        for (int mt = 0; mt < 4; ++mt)
#pragma unroll
            for (int i = 0; i < 4; ++i) {
                int row = m0 + wr * 64 + mt * 16 + qd * 4 + i;
                outp[(size_t)row * TD + col] = acc[mt][nt][i] + bi;
            }
    }
}

// ---------------------------------------------------------------------------
// Flash attention, causal, 32x32-MFMA, KV-SPLIT for uniform load:
// every q-tile qt (128 rows) has its KV range [0, 2qt+2) split into two
// halves of length qt+1. Block (bh, j) processes half-0 of tile qt=j
// (j+1 iters) then half-1 of tile qt=15-j (16-j iters): EXACTLY 17 iters
// per block -> all 512 blocks co-resident (2/CU, 8 waves/CU) start to end.
// K/V staging is double-buffered (2-phase pipeline). Each half writes
// partial O (bf16) and partial l (fp32); combine kernel adds + normalizes.
// ---------------------------------------------------------------------------
__global__ __launch_bounds__(256, 2)
void attn_fwd(const short* __restrict__ qh, const short* __restrict__ kh,
              const short* __restrict__ vt, short* __restrict__ po,
              float* __restrict__ pl)
{
    __shared__ __attribute__((aligned(16))) short Ks[2][64 * 128];  // [key][hd]
    __shared__ __attribute__((aligned(16))) short Vs[2][128 * 64];  // [hd][key]

    const int tid = threadIdx.x;
    const int lane = tid & 63, wid = tid >> 6;   // 4 waves
    const int l31 = lane & 31, h = lane >> 5;
    const int sw7 = l31 & 7;

    const int bi = blockIdx.x;
    const int bh = bi & 31;          // bh%8 == bi%8 -> all 16 blocks of a bh
    const int j  = bi >> 5;          // land on one XCD (K/V L2-resident)
    const size_t bho = (size_t)bh * TT * THD;

    for (int u = 0; u < 2; ++u) {
        const int qt  = u ? (15 - j) : j;
        const int kv0 = u ? (qt + 1) : 0;
        const int kv1 = u ? (2 * qt + 2) : (j + 1);

        // Q B-frags for this tile: B[k=hd][n=q=l31]
        short8 qf[8];
        {
            const short* qp = qh + bho + (size_t)(qt * 128 + wid * 32 + l31) * THD;
#pragma unroll
            for (int ks = 0; ks < 8; ++ks)
                qf[ks] = *(const short8*)(qp + ks * 16 + h * 8);
        }
        float16v o[4];
#pragma unroll
        for (int db = 0; db < 4; ++db)
#pragma unroll
            for (int r = 0; r < 16; ++r) o[db][r] = 0.f;
        float li = 0.f;

        // prologue: stage first tile into buf 0
        {
            const short* kbase = kh + bho + (size_t)kv0 * 64 * THD;
            const short* vbase = vt + (size_t)bh * THD * TT + (size_t)kv0 * 64;
#pragma unroll
            for (int p = 0; p < 4; ++p) {
                int ch = wid * 4 + p;
                int kr = ch * 4 + (lane >> 4);
                int kg = (lane & 15) ^ (kr & 7);
                async16(kbase + (size_t)kr * THD + kg * 8, &Ks[0][ch * 512]);
                int vr = ch * 8 + (lane >> 3);
                int vg = (lane & 7) ^ (vr & 7);
                async16(vbase + (size_t)vr * TT + vg * 8, &Vs[0][ch * 512]);
            }
        }
        __syncthreads();   // drains vmcnt (compiler) + joins waves

        int cur = 0;
        for (int kv = kv0; kv < kv1; ++kv) {
            // issue next tile's loads into the other buffer (hidden by compute)
            if (kv + 1 < kv1) {
                const short* kbase = kh + bho + (size_t)(kv + 1) * 64 * THD;
                const short* vbase = vt + (size_t)bh * THD * TT +
                                     (size_t)(kv + 1) * 64;
#pragma unroll
                for (int p = 0; p < 4; ++p) {
                    int ch = wid * 4 + p;
                    int kr = ch * 4 + (lane >> 4);
                    int kg = (lane & 15) ^ (kr & 7);
                    async16(kbase + (size_t)kr * THD + kg * 8,
                            &Ks[cur ^ 1][ch * 512]);
                    int vr = ch * 8 + (lane >> 3);
                    int vg = (lane & 7) ^ (vr & 7);
                    async16(vbase + (size_t)vr * TT + vg * 8,
                            &Vs[cur ^ 1][ch * 512]);
                }
            }

            const short* Kc = Ks[cur];
            const short* Vc = Vs[cur];

            // S^T = K * Q^T : A = K (m=key), B = Q (n=q). 2 key-blocks of 32.
            float16v s[2];
#pragma unroll
            for (int kb = 0; kb < 2; ++kb)
#pragma unroll
                for (int r = 0; r < 16; ++r) s[kb][r] = 0.f;
#pragma unroll
            for (int ks = 0; ks < 8; ++ks) {
                int cidx = ((ks * 2 + h) ^ sw7) * 8;
                short8 kf0 = *(const short8*)&Kc[l31 * 128 + cidx];
                short8 kf1 = *(const short8*)&Kc[(32 + l31) * 128 + cidx];
                s[0] = __builtin_amdgcn_mfma_f32_32x32x16_bf16(kf0, qf[ks], s[0], 0, 0, 0);
                s[1] = __builtin_amdgcn_mfma_f32_32x32x16_bf16(kf1, qf[ks], s[1], 0, 0, 0);
            }

            if (kv >= 2 * qt) {   // diagonal region: elementwise causal mask
                int q = qt * 128 + wid * 32 + l31;
#pragma unroll
                for (int r = 0; r < 16; ++r) {
                    int key = kv * 64 + (r & 3) + 8 * (r >> 2) + 4 * h;
                    if (key > q) s[0][r] = -1e30f;
                    if (key + 32 > q) s[1][r] = -1e30f;
                }
            }

            // P = exp2(S^T) (log2e folded into Q) -> directly PV A-frags
#pragma unroll
            for (int st = 0; st < 8; ++st) {
                float e0 = exp2f(s[st >> 2][(st & 3) * 4 + 0]);
                float e1 = exp2f(s[st >> 2][(st & 3) * 4 + 1]);
                float e2 = exp2f(s[st >> 2][(st & 3) * 4 + 2]);
                float e3 = exp2f(s[st >> 2][(st & 3) * 4 + 3]);
                li += (e0 + e1) + (e2 + e3);
                short4v ap;
                ap[0] = f2bf(e0); ap[1] = f2bf(e1);
                ap[2] = f2bf(e2); ap[3] = f2bf(e3);
#pragma unroll
                for (int db = 0; db < 4; ++db) {
                    short4v vf = *(const short4v*)&Vc[(db * 32 + l31) * 64 +
                                                      ((st ^ sw7) * 8) + h * 4];
                    o[db] = __builtin_amdgcn_mfma_f32_32x32x8bf16_1k(ap, vf, o[db], 0, 0, 0);
                }
            }
            __syncthreads();   // staged loads drained + all reads of cur done
            cur ^= 1;
        }

        // ---- write partial (O bf16, l fp32) for slot (bh, qt, u) ----
        li += __shfl_xor(li, 32);
        const int slot = (bh * 16 + qt) * 2 + u;
        if (h == 0) pl[slot * 128 + wid * 32 + l31] = li;
        short* pop = po + (size_t)slot * 16384 + (size_t)(wid * 32) * 128 + l31;
#pragma unroll
        for (int r = 0; r < 16; ++r) {
            int ql = (r & 3) + 8 * (r >> 2) + 4 * h;
#pragma unroll
            for (int db = 0; db < 4; ++db)
                pop[(size_t)ql * 128 + db * 32] = f2bf(o[db][r]);
        }
    }
}

// ---------------------------------------------------------------------------
// Combine the two KV-halves: ctx = (oA + oB) / (lA + lB), bf16 out.
// ---------------------------------------------------------------------------
__global__ __launch_bounds__(256)
void combine(const short* __restrict__ po, const float* __restrict__ pl,
             short* __restrict__ ctx)
{
    const unsigned i = blockIdx.x * 256 + threadIdx.x;   // [0, 1<<20)
    const int hdv = i & 15;
    const int q   = (i >> 4) & 127;
    const int qt  = (i >> 11) & 15;
    const int bh  = i >> 15;                              // [0,32)
    const int tile = bh * 16 + qt;
    const size_t base = (size_t)tile * 2 * 16384 + (size_t)q * 128 + hdv * 8;
    short8 a = *(const short8*)&po[base];
    short8 b = *(const short8*)&po[base + 16384];
    const float inv = 1.f / (pl[tile * 2 * 128 + q] + pl[(tile * 2 + 1) * 128 + q]);
    short8 r;
#pragma unroll
    for (int k = 0; k < 8; ++k)
        r[k] = f2bf((bf2f(a[k]) + bf2f(b[k])) * inv);
    const int b_ = bh >> 3, h_ = bh & 7, t = qt * 128 + q;
    *(short8*)&ctx[((size_t)(b_ * TT + t)) * TD + h_ * THD + hdv * 8] = r;
}

extern "C" void kernel_launch(void* const* d_in, const int* in_sizes, int n_in,
                              void* d_out, int out_size, void* d_ws, size_t ws_size,
                              hipStream_t stream) {
    (void)in_sizes; (void)n_in; (void)out_size; (void)ws_size;
    const float* x  = (const float*)d_in[0];
    const float* y  = (const float*)d_in[1];
    const float* Wq = (const float*)d_in[2];
    const float* bq = (const float*)d_in[3];
    const float* Wk = (const float*)d_in[4];
    const float* bk = (const float*)d_in[5];
    const float* Wv = (const float*)d_in[6];
    const float* bv = (const float*)d_in[7];
    const float* Wo = (const float*)d_in[8];
    const float* bo = (const float*)d_in[9];
    float* out = (float*)d_out;

    const size_t SZ = (size_t)TB * TT * TD;     // 8,388,608
    const size_t WSZ = (size_t)TD * TD;         // 1,048,576
    short* xyb = (short*)d_ws;                  // x,y bf16 (33.5 MB)
    short* wb  = xyb + 2 * SZ;                  // weights bf16 (8 MB)
    short* qh  = wb + 4 * WSZ;
    short* kh  = qh + SZ;
    short* vt  = kh + SZ;
    float* pl  = (float*)(vt + SZ);             // partial l, 512 KB
    short* po  = xyb;                           // partial O: aliases dead x/y
    short* ctx = qh;                            // aliases qh (dead after attn)

    hipLaunchKernelGGL(cvtall, dim3(SZ / 2048, 6), dim3(256), 0, stream,
                       x, y, Wq, Wk, Wv, Wo, xyb, wb);
    hipLaunchKernelGGL(gemm_qkv8, dim3(768), dim3(512), 0, stream,
                       xyb, wb, bq, bk, bv, qh, kh, vt);
    hipLaunchKernelGGL(attn_fwd, dim3(512), dim3(256), 0, stream, qh, kh, vt, po, pl);
    hipLaunchKernelGGL(combine, dim3(4096), dim3(256), 0, stream, po, pl, ctx);
    hipLaunchKernelGGL(gemm_out8, dim3(256), dim3(512), 0, stream,
                       ctx, wb + 3 * WSZ, bo, out);
}